// Round 1
// baseline (205.300 us; speedup 1.0000x reference)
//
#include <hip/hip_runtime.h>
#include <hip/hip_bf16.h>

// Problem dims (fixed by the reference)
#define L_DIM 2
#define B_DIM 32
#define T_DIM 2048
#define H_DIM 512

// Fast tanh: tanh(x) = 1 - 2/(exp(2x)+1), exp via v_exp_f32 (2^y), rcp via v_rcp_f32.
// abs err ~1e-7 — negligible vs 3.4e-3 harness threshold.
__device__ __forceinline__ float fast_tanh(float x) {
    float t = __builtin_amdgcn_exp2f(x * 2.8853900817779268f); // e^(2x)
    return 1.0f - 2.0f * __builtin_amdgcn_rcpf(t + 1.0f);
}

// ---------------------------------------------------------------------------
// Kernel A: hidden_attn[b][i] = bh[i] + sum_j (0.5*(hidden[0,b,j]+hidden[1,b,j])) * Wh[i][j]
// One wave per output element. wave = i*B + b so consecutive waves reuse the same Wh row (L1).
// ---------------------------------------------------------------------------
__global__ __launch_bounds__(256) void proj_kernel(
        const float* __restrict__ hidden,   // [L,B,H]
        const float* __restrict__ Wh,       // [H,H]
        const float* __restrict__ bh,       // [H]
        float* __restrict__ hidden_attn) {  // [B,H]
    int wave = (blockIdx.x * blockDim.x + threadIdx.x) >> 6;   // 0 .. B*H-1
    int lane = threadIdx.x & 63;
    int i = wave >> 5;          // output feature (0..511)
    int b = wave & 31;          // batch

    const float* h0 = hidden + (size_t)b * H_DIM + lane * 8;
    const float* h1 = hidden + (size_t)(B_DIM + b) * H_DIM + lane * 8;
    const float* wr = Wh + (size_t)i * H_DIM + lane * 8;

    float4 a0 = *(const float4*)(h0);
    float4 a1 = *(const float4*)(h0 + 4);
    float4 c0 = *(const float4*)(h1);
    float4 c1 = *(const float4*)(h1 + 4);
    float4 w0 = *(const float4*)(wr);
    float4 w1 = *(const float4*)(wr + 4);

    float acc = 0.f;
    acc += 0.5f * (a0.x + c0.x) * w0.x;
    acc += 0.5f * (a0.y + c0.y) * w0.y;
    acc += 0.5f * (a0.z + c0.z) * w0.z;
    acc += 0.5f * (a0.w + c0.w) * w0.w;
    acc += 0.5f * (a1.x + c1.x) * w1.x;
    acc += 0.5f * (a1.y + c1.y) * w1.y;
    acc += 0.5f * (a1.z + c1.z) * w1.z;
    acc += 0.5f * (a1.w + c1.w) * w1.w;

    #pragma unroll
    for (int off = 32; off; off >>= 1) acc += __shfl_down(acc, off);

    if (lane == 0) hidden_attn[(size_t)b * H_DIM + i] = acc + bh[i];
}

// ---------------------------------------------------------------------------
// Kernel B: energy[b][t] = bo + sum_h Wo[h] * tanh(eo[t,b,h] + hidden_attn[b,h])
// One wave per (t,b); t-major so consecutive waves read contiguous memory.
// Each lane handles 8 contiguous h (2x float4).
// ---------------------------------------------------------------------------
__global__ __launch_bounds__(256) void energy_kernel(
        const float* __restrict__ eo,           // [T,B,H]
        const float* __restrict__ hidden_attn,  // [B,H]
        const float* __restrict__ Wo,           // [H]
        const float* __restrict__ bo,           // [1]
        float* __restrict__ energy) {           // [B,T]
    int p = (int)((blockIdx.x * blockDim.x + threadIdx.x) >> 6); // wave id = t*B + b
    int lane = threadIdx.x & 63;
    int t = p >> 5;     // /B_DIM
    int b = p & 31;

    const float* src = eo + ((size_t)t * B_DIM + b) * H_DIM + lane * 8;
    const float* ha  = hidden_attn + (size_t)b * H_DIM + lane * 8;
    const float* wo  = Wo + lane * 8;

    float4 e0 = *(const float4*)(src);
    float4 e1 = *(const float4*)(src + 4);
    float4 a0 = *(const float4*)(ha);
    float4 a1 = *(const float4*)(ha + 4);
    float4 w0 = *(const float4*)(wo);
    float4 w1 = *(const float4*)(wo + 4);

    float acc = 0.f;
    acc += w0.x * fast_tanh(e0.x + a0.x);
    acc += w0.y * fast_tanh(e0.y + a0.y);
    acc += w0.z * fast_tanh(e0.z + a0.z);
    acc += w0.w * fast_tanh(e0.w + a0.w);
    acc += w1.x * fast_tanh(e1.x + a1.x);
    acc += w1.y * fast_tanh(e1.y + a1.y);
    acc += w1.z * fast_tanh(e1.z + a1.z);
    acc += w1.w * fast_tanh(e1.w + a1.w);

    #pragma unroll
    for (int off = 32; off; off >>= 1) acc += __shfl_down(acc, off);

    if (lane == 0) energy[(size_t)b * T_DIM + t] = acc + bo[0];
}

// ---------------------------------------------------------------------------
// Kernel C: ragged masked softmax over t for each b; zeros past enc_len[b].
// One 256-thread block per b; 8 elements per thread held in registers.
// ---------------------------------------------------------------------------
__global__ __launch_bounds__(256) void softmax_kernel(
        const float* __restrict__ energy,  // [B,T]
        const int* __restrict__ enc_len,   // [B]
        float* __restrict__ out) {         // [B,T]
    int b = blockIdx.x;
    int tid = threadIdx.x;
    int len = enc_len[b];

    const float* row = energy + (size_t)b * T_DIM;
    int base = tid * 8;

    float4 r0 = *(const float4*)(row + base);
    float4 r1 = *(const float4*)(row + base + 4);
    float v[8] = {r0.x, r0.y, r0.z, r0.w, r1.x, r1.y, r1.z, r1.w};

    float m = -INFINITY;
    #pragma unroll
    for (int k = 0; k < 8; ++k) {
        if (base + k >= len) v[k] = -INFINITY;
        m = fmaxf(m, v[k]);
    }

    __shared__ float red_max[4];
    __shared__ float red_sum[4];

    // block max
    #pragma unroll
    for (int off = 32; off; off >>= 1) m = fmaxf(m, __shfl_down(m, off));
    int wid = tid >> 6;
    if ((tid & 63) == 0) red_max[wid] = m;
    __syncthreads();
    m = fmaxf(fmaxf(red_max[0], red_max[1]), fmaxf(red_max[2], red_max[3]));

    // exp and block sum
    float s = 0.f;
    #pragma unroll
    for (int k = 0; k < 8; ++k) {
        float ex = (base + k < len) ? __builtin_amdgcn_exp2f((v[k] - m) * 1.4426950408889634f) : 0.f;
        v[k] = ex;
        s += ex;
    }
    #pragma unroll
    for (int off = 32; off; off >>= 1) s += __shfl_down(s, off);
    if ((tid & 63) == 0) red_sum[wid] = s;
    __syncthreads();
    s = (red_sum[0] + red_sum[1]) + (red_sum[2] + red_sum[3]);

    float inv = 1.0f / s;
    float4 o0 = {v[0] * inv, v[1] * inv, v[2] * inv, v[3] * inv};
    float4 o1 = {v[4] * inv, v[5] * inv, v[6] * inv, v[7] * inv};
    *(float4*)(out + (size_t)b * T_DIM + base)     = o0;
    *(float4*)(out + (size_t)b * T_DIM + base + 4) = o1;
}

extern "C" void kernel_launch(void* const* d_in, const int* in_sizes, int n_in,
                              void* d_out, int out_size, void* d_ws, size_t ws_size,
                              hipStream_t stream) {
    const float* hidden  = (const float*)d_in[0];  // [L,B,H]
    const float* eo      = (const float*)d_in[1];  // [T,B,H]
    const int*   enc_len = (const int*)d_in[2];    // [B] (jax x64 off -> int32)
    const float* Wh      = (const float*)d_in[3];  // [H,H]
    const float* bh      = (const float*)d_in[4];  // [H]
    const float* Wo      = (const float*)d_in[5];  // [1,H]
    const float* bo      = (const float*)d_in[6];  // [1]
    float* out = (float*)d_out;                    // [B,T,1]

    float* hidden_attn = (float*)d_ws;                     // B*H floats (64 KB)
    float* energy      = hidden_attn + B_DIM * H_DIM;      // B*T floats (256 KB)

    // A: 16384 waves (one per (i,b)), 4 waves/block
    proj_kernel<<<(B_DIM * H_DIM) / 4, 256, 0, stream>>>(hidden, Wh, bh, hidden_attn);
    // B: 65536 waves (one per (t,b)), 4 waves/block
    energy_kernel<<<(B_DIM * T_DIM) / 4, 256, 0, stream>>>(eo, hidden_attn, Wo, bo, energy);
    // C: one block per batch row
    softmax_kernel<<<B_DIM, 256, 0, stream>>>(energy, enc_len, out);
}

// Round 3
// 193.621 us; speedup vs baseline: 1.0603x; 1.0603x over previous
//
#include <hip/hip_runtime.h>
#include <hip/hip_bf16.h>

// Problem dims (fixed by the reference)
#define L_DIM 2
#define B_DIM 32
#define T_DIM 2048
#define H_DIM 512

// Fast tanh: tanh(x) = 1 - 2/(exp(2x)+1), exp via v_exp_f32 (2^y), rcp via v_rcp_f32.
// abs err ~1e-7 — negligible vs 3.4e-3 harness threshold.
__device__ __forceinline__ float fast_tanh(float x) {
    float t = __builtin_amdgcn_exp2f(x * 2.8853900817779268f); // e^(2x)
    return 1.0f - 2.0f * __builtin_amdgcn_rcpf(t + 1.0f);
}

// ---------------------------------------------------------------------------
// Kernel A: hidden_attn[b][i] = bh[i] + sum_j (0.5*(hidden[0,b,j]+hidden[1,b,j])) * Wh[i][j]
// One wave per output element. wave = i*B + b so consecutive waves reuse the same Wh row.
// ---------------------------------------------------------------------------
__global__ __launch_bounds__(256) void proj_kernel(
        const float* __restrict__ hidden,   // [L,B,H]
        const float* __restrict__ Wh,       // [H,H]
        const float* __restrict__ bh,       // [H]
        float* __restrict__ hidden_attn) {  // [B,H]
    int wave = (blockIdx.x * blockDim.x + threadIdx.x) >> 6;   // 0 .. B*H-1
    int lane = threadIdx.x & 63;
    int i = wave >> 5;          // output feature (0..511)
    int b = wave & 31;          // batch

    const float* h0 = hidden + (size_t)b * H_DIM + lane * 8;
    const float* h1 = hidden + (size_t)(B_DIM + b) * H_DIM + lane * 8;
    const float* wr = Wh + (size_t)i * H_DIM + lane * 8;

    float4 a0 = *(const float4*)(h0);
    float4 a1 = *(const float4*)(h0 + 4);
    float4 c0 = *(const float4*)(h1);
    float4 c1 = *(const float4*)(h1 + 4);
    float4 w0 = *(const float4*)(wr);
    float4 w1 = *(const float4*)(wr + 4);

    float acc = 0.f;
    acc += 0.5f * (a0.x + c0.x) * w0.x;
    acc += 0.5f * (a0.y + c0.y) * w0.y;
    acc += 0.5f * (a0.z + c0.z) * w0.z;
    acc += 0.5f * (a0.w + c0.w) * w0.w;
    acc += 0.5f * (a1.x + c1.x) * w1.x;
    acc += 0.5f * (a1.y + c1.y) * w1.y;
    acc += 0.5f * (a1.z + c1.z) * w1.z;
    acc += 0.5f * (a1.w + c1.w) * w1.w;

    #pragma unroll
    for (int off = 32; off; off >>= 1) acc += __shfl_down(acc, off);

    if (lane == 0) hidden_attn[(size_t)b * H_DIM + i] = acc + bh[i];
}

// ---------------------------------------------------------------------------
// Kernel B: energy[b][t] = bo + sum_h Wo[h] * tanh(eo[t,b,h] + hidden_attn[b,h])
// Block owns (b, 4 consecutive t). t >= enc_len[b] is DON'T-CARE in the
// reference (masked to -inf before softmax, output forced to 0), so fully
// masked blocks exit without touching HBM — expected ~50% traffic cut.
// ---------------------------------------------------------------------------
__global__ __launch_bounds__(256) void energy_kernel(
        const float* __restrict__ eo,           // [T,B,H]
        const float* __restrict__ hidden_attn,  // [B,H]
        const float* __restrict__ Wo,           // [H]
        const float* __restrict__ bo,           // [1]
        const int* __restrict__ enc_len,        // [B]
        float* __restrict__ energy) {           // [B,T]
    int b    = blockIdx.x >> 9;        // blockIdx / (T/4)
    int tblk = blockIdx.x & 511;
    int len  = enc_len[b];             // block-uniform
    int t0   = tblk << 2;
    if (t0 >= len) return;             // whole block masked: no HBM traffic

    int wv   = threadIdx.x >> 6;
    int lane = threadIdx.x & 63;
    int t    = t0 + wv;
    if (t >= len) return;              // wave-level mask in boundary block

    const float* src = eo + ((size_t)t * B_DIM + b) * H_DIM + lane * 8;
    const float* ha  = hidden_attn + (size_t)b * H_DIM + lane * 8;
    const float* wo  = Wo + lane * 8;

    float4 e0 = *(const float4*)(src);
    float4 e1 = *(const float4*)(src + 4);
    float4 a0 = *(const float4*)(ha);
    float4 a1 = *(const float4*)(ha + 4);
    float4 w0 = *(const float4*)(wo);
    float4 w1 = *(const float4*)(wo + 4);

    float acc = 0.f;
    acc += w0.x * fast_tanh(e0.x + a0.x);
    acc += w0.y * fast_tanh(e0.y + a0.y);
    acc += w0.z * fast_tanh(e0.z + a0.z);
    acc += w0.w * fast_tanh(e0.w + a0.w);
    acc += w1.x * fast_tanh(e1.x + a1.x);
    acc += w1.y * fast_tanh(e1.y + a1.y);
    acc += w1.z * fast_tanh(e1.z + a1.z);
    acc += w1.w * fast_tanh(e1.w + a1.w);

    #pragma unroll
    for (int off = 32; off; off >>= 1) acc += __shfl_down(acc, off);

    if (lane == 0) energy[(size_t)b * T_DIM + t] = acc + bo[0];
}

// ---------------------------------------------------------------------------
// Kernel C: ragged masked softmax over t for each b; zeros past enc_len[b].
// One 256-thread block per b; 8 elements per thread held in registers.
// energy[t >= len] is uninitialized poison (finite, not NaN) — masked before use.
// ---------------------------------------------------------------------------
__global__ __launch_bounds__(256) void softmax_kernel(
        const float* __restrict__ energy,  // [B,T]
        const int* __restrict__ enc_len,   // [B]
        float* __restrict__ out) {         // [B,T]
    int b = blockIdx.x;
    int tid = threadIdx.x;
    int len = enc_len[b];

    const float* row = energy + (size_t)b * T_DIM;
    int base = tid * 8;

    float4 r0 = *(const float4*)(row + base);
    float4 r1 = *(const float4*)(row + base + 4);
    float v[8] = {r0.x, r0.y, r0.z, r0.w, r1.x, r1.y, r1.z, r1.w};

    float m = -INFINITY;
    #pragma unroll
    for (int k = 0; k < 8; ++k) {
        if (base + k >= len) v[k] = -INFINITY;
        m = fmaxf(m, v[k]);
    }

    __shared__ float red_max[4];
    __shared__ float red_sum[4];

    // block max
    #pragma unroll
    for (int off = 32; off; off >>= 1) m = fmaxf(m, __shfl_down(m, off));
    int wid = tid >> 6;
    if ((tid & 63) == 0) red_max[wid] = m;
    __syncthreads();
    m = fmaxf(fmaxf(red_max[0], red_max[1]), fmaxf(red_max[2], red_max[3]));

    // exp and block sum
    float s = 0.f;
    #pragma unroll
    for (int k = 0; k < 8; ++k) {
        float ex = (base + k < len) ? __builtin_amdgcn_exp2f((v[k] - m) * 1.4426950408889634f) : 0.f;
        v[k] = ex;
        s += ex;
    }
    #pragma unroll
    for (int off = 32; off; off >>= 1) s += __shfl_down(s, off);
    if ((tid & 63) == 0) red_sum[wid] = s;
    __syncthreads();
    s = (red_sum[0] + red_sum[1]) + (red_sum[2] + red_sum[3]);

    float inv = 1.0f / s;
    float4 o0 = {v[0] * inv, v[1] * inv, v[2] * inv, v[3] * inv};
    float4 o1 = {v[4] * inv, v[5] * inv, v[6] * inv, v[7] * inv};
    *(float4*)(out + (size_t)b * T_DIM + base)     = o0;
    *(float4*)(out + (size_t)b * T_DIM + base + 4) = o1;
}

extern "C" void kernel_launch(void* const* d_in, const int* in_sizes, int n_in,
                              void* d_out, int out_size, void* d_ws, size_t ws_size,
                              hipStream_t stream) {
    const float* hidden  = (const float*)d_in[0];  // [L,B,H]
    const float* eo      = (const float*)d_in[1];  // [T,B,H]
    const int*   enc_len = (const int*)d_in[2];    // [B] (jax x64 off -> int32)
    const float* Wh      = (const float*)d_in[3];  // [H,H]
    const float* bh      = (const float*)d_in[4];  // [H]
    const float* Wo      = (const float*)d_in[5];  // [1,H]
    const float* bo      = (const float*)d_in[6];  // [1]
    float* out = (float*)d_out;                    // [B,T,1]

    float* hidden_attn = (float*)d_ws;                     // B*H floats (64 KB)
    float* energy      = hidden_attn + B_DIM * H_DIM;      // B*T floats (256 KB)

    // A: 16384 waves (one per (i,b)), 4 waves/block
    proj_kernel<<<(B_DIM * H_DIM) / 4, 256, 0, stream>>>(hidden, Wh, bh, hidden_attn);
    // B: block = (b, 4 t's); grid = 32 * 512
    energy_kernel<<<B_DIM * (T_DIM / 4), 256, 0, stream>>>(eo, hidden_attn, Wo, bo, enc_len, energy);
    // C: one block per batch row
    softmax_kernel<<<B_DIM, 256, 0, stream>>>(energy, enc_len, out);
}

// Round 6
// 193.092 us; speedup vs baseline: 1.0632x; 1.0027x over previous
//
#include <hip/hip_runtime.h>
#include <hip/hip_bf16.h>

// Problem dims (fixed by the reference)
#define L_DIM 2
#define B_DIM 32
#define T_DIM 2048
#define H_DIM 512

// Fast tanh: tanh(x) = 1 - 2/(exp(2x)+1), exp via v_exp_f32, rcp via v_rcp_f32.
__device__ __forceinline__ float fast_tanh(float x) {
    float t = __builtin_amdgcn_exp2f(x * 2.8853900817779268f); // e^(2x)
    return 1.0f - 2.0f * __builtin_amdgcn_rcpf(t + 1.0f);
}

// ---------------------------------------------------------------------------
// Kernel A: hidden_attn[b][i] = bh[i] + sum_j mean_j * Wh[i][j]
// One wave per TWO output features (i, i+1) — hidden loads shared.
// ---------------------------------------------------------------------------
__global__ __launch_bounds__(256) void proj_kernel(
        const float* __restrict__ hidden,   // [L,B,H]
        const float* __restrict__ Wh,       // [H,H]
        const float* __restrict__ bh,       // [H]
        float* __restrict__ hidden_attn) {  // [B,H]
    int wave = (blockIdx.x * blockDim.x + threadIdx.x) >> 6;   // 0 .. B*H/2-1
    int lane = threadIdx.x & 63;
    int i = (wave >> 5) << 1;   // output features i, i+1
    int b = wave & 31;          // batch

    const float* h0 = hidden + (size_t)b * H_DIM + lane * 8;
    const float* h1 = hidden + (size_t)(B_DIM + b) * H_DIM + lane * 8;
    float4 a0 = *(const float4*)(h0);
    float4 a1 = *(const float4*)(h0 + 4);
    float4 c0 = *(const float4*)(h1);
    float4 c1 = *(const float4*)(h1 + 4);

    float m[8];
    m[0] = 0.5f * (a0.x + c0.x); m[1] = 0.5f * (a0.y + c0.y);
    m[2] = 0.5f * (a0.z + c0.z); m[3] = 0.5f * (a0.w + c0.w);
    m[4] = 0.5f * (a1.x + c1.x); m[5] = 0.5f * (a1.y + c1.y);
    m[6] = 0.5f * (a1.z + c1.z); m[7] = 0.5f * (a1.w + c1.w);

    const float* wr0 = Wh + (size_t)i * H_DIM + lane * 8;
    float4 p0 = *(const float4*)(wr0);
    float4 p1 = *(const float4*)(wr0 + 4);
    float4 q0 = *(const float4*)(wr0 + H_DIM);
    float4 q1 = *(const float4*)(wr0 + H_DIM + 4);

    float acc0 = m[0]*p0.x + m[1]*p0.y + m[2]*p0.z + m[3]*p0.w
               + m[4]*p1.x + m[5]*p1.y + m[6]*p1.z + m[7]*p1.w;
    float acc1 = m[0]*q0.x + m[1]*q0.y + m[2]*q0.z + m[3]*q0.w
               + m[4]*q1.x + m[5]*q1.y + m[6]*q1.z + m[7]*q1.w;

    #pragma unroll
    for (int off = 32; off; off >>= 1) {
        acc0 += __shfl_down(acc0, off);
        acc1 += __shfl_down(acc1, off);
    }

    if (lane == 0) {
        hidden_attn[(size_t)b * H_DIM + i]     = acc0 + bh[i];
        hidden_attn[(size_t)b * H_DIM + i + 1] = acc1 + bh[i + 1];
    }
}

// ---------------------------------------------------------------------------
// Kernel B: energy[b][t] = bo + sum_h Wo[h] * tanh(eo[t,b,h] + hidden_attn[b,h])
// Block owns (b, 8 consecutive t); each wave TWO t-rows (ha/wo loads amortized).
// t >= enc_len[b] is DON'T-CARE (masked before softmax) — masked blocks/waves
// exit without touching HBM.
// ---------------------------------------------------------------------------
__global__ __launch_bounds__(256) void energy_kernel(
        const float* __restrict__ eo,           // [T,B,H]
        const float* __restrict__ hidden_attn,  // [B,H]
        const float* __restrict__ Wo,           // [H]
        const float* __restrict__ bo,           // [1]
        const int* __restrict__ enc_len,        // [B]
        float* __restrict__ energy) {           // [B,T]
    int b    = blockIdx.x >> 8;        // blockIdx / (T/8)
    int tblk = blockIdx.x & 255;
    int len  = enc_len[b];             // block-uniform
    int t0   = tblk << 3;
    if (t0 >= len) return;             // whole block masked: no HBM traffic

    int wv   = threadIdx.x >> 6;
    int lane = threadIdx.x & 63;
    int t    = t0 + (wv << 1);
    if (t >= len) return;              // wave-level mask
    bool do2 = (t + 1 < len);          // wave-uniform

    const float* src = eo + ((size_t)t * B_DIM + b) * H_DIM + lane * 8;
    const float* ha  = hidden_attn + (size_t)b * H_DIM + lane * 8;
    const float* wo  = Wo + lane * 8;

    float4 e0 = *(const float4*)(src);
    float4 e1 = *(const float4*)(src + 4);
    float4 a0 = *(const float4*)(ha);
    float4 a1 = *(const float4*)(ha + 4);
    float4 w0 = *(const float4*)(wo);
    float4 w1 = *(const float4*)(wo + 4);

    float acc0 = 0.f, acc1 = 0.f;
    acc0 += w0.x * fast_tanh(e0.x + a0.x);
    acc0 += w0.y * fast_tanh(e0.y + a0.y);
    acc0 += w0.z * fast_tanh(e0.z + a0.z);
    acc0 += w0.w * fast_tanh(e0.w + a0.w);
    acc0 += w1.x * fast_tanh(e1.x + a1.x);
    acc0 += w1.y * fast_tanh(e1.y + a1.y);
    acc0 += w1.z * fast_tanh(e1.z + a1.z);
    acc0 += w1.w * fast_tanh(e1.w + a1.w);

    if (do2) {
        const float* src1 = src + (size_t)B_DIM * H_DIM;  // row t+1
        float4 f0 = *(const float4*)(src1);
        float4 f1 = *(const float4*)(src1 + 4);
        acc1 += w0.x * fast_tanh(f0.x + a0.x);
        acc1 += w0.y * fast_tanh(f0.y + a0.y);
        acc1 += w0.z * fast_tanh(f0.z + a0.z);
        acc1 += w0.w * fast_tanh(f0.w + a0.w);
        acc1 += w1.x * fast_tanh(f1.x + a1.x);
        acc1 += w1.y * fast_tanh(f1.y + a1.y);
        acc1 += w1.z * fast_tanh(f1.z + a1.z);
        acc1 += w1.w * fast_tanh(f1.w + a1.w);
    }

    #pragma unroll
    for (int off = 32; off; off >>= 1) {
        acc0 += __shfl_down(acc0, off);
        acc1 += __shfl_down(acc1, off);
    }

    if (lane == 0) {
        float bias = bo[0];
        energy[(size_t)b * T_DIM + t] = acc0 + bias;
        if (do2) energy[(size_t)b * T_DIM + t + 1] = acc1 + bias;
    }
}

// ---------------------------------------------------------------------------
// Kernel C: ragged masked softmax over t for each b; zeros past enc_len[b].
// One 256-thread block per b; 8 elements per thread held in registers.
// energy[t >= len] is uninitialized poison (finite, not NaN) — masked before use.
// ---------------------------------------------------------------------------
__global__ __launch_bounds__(256) void softmax_kernel(
        const float* __restrict__ energy,  // [B,T]
        const int* __restrict__ enc_len,   // [B]
        float* __restrict__ out) {         // [B,T]
    int b = blockIdx.x;
    int tid = threadIdx.x;
    int len = enc_len[b];

    const float* row = energy + (size_t)b * T_DIM;
    int base = tid * 8;

    float4 r0 = *(const float4*)(row + base);
    float4 r1 = *(const float4*)(row + base + 4);
    float v[8] = {r0.x, r0.y, r0.z, r0.w, r1.x, r1.y, r1.z, r1.w};

    float m = -INFINITY;
    #pragma unroll
    for (int k = 0; k < 8; ++k) {
        if (base + k >= len) v[k] = -INFINITY;
        m = fmaxf(m, v[k]);
    }

    __shared__ float red_max[4];
    __shared__ float red_sum[4];

    // block max
    #pragma unroll
    for (int off = 32; off; off >>= 1) m = fmaxf(m, __shfl_down(m, off));
    int wid = tid >> 6;
    if ((tid & 63) == 0) red_max[wid] = m;
    __syncthreads();
    m = fmaxf(fmaxf(red_max[0], red_max[1]), fmaxf(red_max[2], red_max[3]));

    // exp and block sum
    float s = 0.f;
    #pragma unroll
    for (int k = 0; k < 8; ++k) {
        float ex = (base + k < len) ? __builtin_amdgcn_exp2f((v[k] - m) * 1.4426950408889634f) : 0.f;
        v[k] = ex;
        s += ex;
    }
    #pragma unroll
    for (int off = 32; off; off >>= 1) s += __shfl_down(s, off);
    if ((tid & 63) == 0) red_sum[wid] = s;
    __syncthreads();
    s = (red_sum[0] + red_sum[1]) + (red_sum[2] + red_sum[3]);

    float inv = 1.0f / s;
    float4 o0 = {v[0] * inv, v[1] * inv, v[2] * inv, v[3] * inv};
    float4 o1 = {v[4] * inv, v[5] * inv, v[6] * inv, v[7] * inv};
    *(float4*)(out + (size_t)b * T_DIM + base)     = o0;
    *(float4*)(out + (size_t)b * T_DIM + base + 4) = o1;
}

extern "C" void kernel_launch(void* const* d_in, const int* in_sizes, int n_in,
                              void* d_out, int out_size, void* d_ws, size_t ws_size,
                              hipStream_t stream) {
    const float* hidden  = (const float*)d_in[0];  // [L,B,H]
    const float* eo      = (const float*)d_in[1];  // [T,B,H]
    const int*   enc_len = (const int*)d_in[2];    // [B] (jax x64 off -> int32)
    const float* Wh      = (const float*)d_in[3];  // [H,H]
    const float* bh      = (const float*)d_in[4];  // [H]
    const float* Wo      = (const float*)d_in[5];  // [1,H]
    const float* bo      = (const float*)d_in[6];  // [1]
    float* out = (float*)d_out;                    // [B,T,1]

    float* hidden_attn = (float*)d_ws;                     // B*H floats (64 KB)
    float* energy      = hidden_attn + B_DIM * H_DIM;      // B*T floats (256 KB)

    // A: 8192 waves (one per (i-pair, b)), 4 waves/block
    proj_kernel<<<(B_DIM * H_DIM / 2) / 4, 256, 0, stream>>>(hidden, Wh, bh, hidden_attn);
    // B: block = (b, 8 t's); wave = 2 t's; grid = 32 * 256
    energy_kernel<<<B_DIM * (T_DIM / 8), 256, 0, stream>>>(eo, hidden_attn, Wo, bo, enc_len, energy);
    // C: one block per batch row
    softmax_kernel<<<B_DIM, 256, 0, stream>>>(energy, enc_len, out);
}